// Round 5
// baseline (1638.172 us; speedup 1.0000x reference)
//
#include <hip/hip_runtime.h>
#include <hip/hip_bf16.h>

typedef __hip_bfloat16 bf16;
typedef __attribute__((ext_vector_type(8))) short short8;
typedef __attribute__((ext_vector_type(4))) short short4v;
typedef __attribute__((ext_vector_type(4))) float f32x4;

#define DEVINL static __device__ __forceinline__

DEVINL float b2f(bf16 x) { return __bfloat162float(x); }
DEVINL bf16 f2b(float x) { return __float2bfloat16(x); }
DEVINL float sb2f(short s) { return b2f(__builtin_bit_cast(bf16, s)); }
DEVINL short f2sb(float x) { return __builtin_bit_cast(short, f2b(x)); }

DEVINL void gload16(const void* g, void* l) {
  __builtin_amdgcn_global_load_lds(
      (const __attribute__((address_space(1))) void*)g,
      (__attribute__((address_space(3))) void*)l, 16, 0, 0);
}

DEVINL float wave_sum(float v) {
#pragma unroll
  for (int o = 32; o > 0; o >>= 1) v += __shfl_down(v, o, 64);
  return v;
}

DEVINL float wave_allsum(float v) {
#pragma unroll
  for (int o = 32; o > 0; o >>= 1) v += __shfl_xor(v, o, 64);
  return v;
}

// Exact-erf GELU via Abramowitz-Stegun 7.1.26 (max abs err 1.5e-7 in erf,
// far below bf16 output rounding). Replaces libm erff (~50+ VALU inst).
DEVINL float gelu_exact(float v) {
  const float z = v * 0.70710678118654752f;
  const float az = fabsf(z);
  const float t = 1.0f / (1.0f + 0.3275911f * az);
  float p = 1.061405429f;
  p = p * t - 1.453152027f;
  p = p * t + 1.421413741f;
  p = p * t - 0.284496736f;
  p = p * t + 0.254829592f;
  const float e = __expf(-z * z);
  const float erf_az = 1.0f - p * t * e;
  const float er = (z < 0.f) ? -erf_az : erf_az;
  return 0.5f * v * (1.0f + er);
}

// ---------------------------------------------------------------------------
// Legacy NT GEMM (64-tile) — retained for the Newton-Schulz chain only.
// MODE 3: split-write hi/lo bf16 (NS gram)   MODE 4: NS update
// ---------------------------------------------------------------------------
template <int MODE, bool SPLIT, int BM>
__global__ __launch_bounds__(256) void gemm_nt(
    const bf16* __restrict__ A0, const bf16* __restrict__ A1,
    const bf16* __restrict__ B0, const bf16* __restrict__ B1,
    int K, int lda, int ldb, long bsA, long bsB, long bsC,
    float alpha, float beta, float* __restrict__ Xf,
    bf16* __restrict__ Whi, bf16* __restrict__ Wlo,
    bf16* __restrict__ Thi, bf16* __restrict__ Tlo) {
  constexpr int BK = 64;
  constexpr int MT = BM / 32;
  constexpr int NLOAD = BM * BK / 2048;
  extern __shared__ char smem[];
  bf16* AsH = (bf16*)smem;
  bf16* BsH = AsH + BM * BK;
  bf16* AsL = BsH + BM * BK;
  bf16* BsL = AsL + BM * BK;

  const int t = threadIdx.x;
  const int lane = t & 63, w = t >> 6;
  const long bz = blockIdx.z;
  const bf16* Ab0 = A0 + bz * bsA;
  const bf16* Bb0 = B0 + bz * bsB;
  const bf16* Ab1 = SPLIT ? (A1 + bz * bsA) : nullptr;
  const bf16* Bb1 = SPLIT ? (B1 + bz * bsB) : nullptr;

  const int row0 = blockIdx.x * BM, col0 = blockIdx.y * BM;
  const int wm = (w >> 1) * (BM / 2), wn = (w & 1) * (BM / 2);
  const int jj = lane >> 4, r16 = lane & 15;

  f32x4 acc[MT][MT] = {};

  for (int k0 = 0; k0 < K; k0 += BK) {
    __syncthreads();
#pragma unroll
    for (int s = 0; s < NLOAD; ++s) {
      const int L = s * 256 + t;
      const int cj = L / BM, m = L % BM;
      const long ga = (long)(row0 + m) * lda + (k0 + cj * 8);
      const long gb = (long)(col0 + m) * ldb + (k0 + cj * 8);
      gload16(Ab0 + ga, AsH + L * 8);
      gload16(Bb0 + gb, BsH + L * 8);
      if (SPLIT) {
        gload16(Ab1 + ga, AsL + L * 8);
        gload16(Bb1 + gb, BsL + L * 8);
      }
    }
    __syncthreads();

#pragma unroll
    for (int kk = 0; kk < BK / 32; ++kk) {
      short8 a[MT], b[MT], al[MT], bl[MT];
#pragma unroll
      for (int mt = 0; mt < MT; ++mt) {
        const int o = (kk * 4 + jj) * BM * 8 + (wm + mt * 16 + r16) * 8;
        a[mt] = *(const short8*)(AsH + o);
        if (SPLIT) al[mt] = *(const short8*)(AsL + o);
      }
#pragma unroll
      for (int nt = 0; nt < MT; ++nt) {
        const int o = (kk * 4 + jj) * BM * 8 + (wn + nt * 16 + r16) * 8;
        b[nt] = *(const short8*)(BsH + o);
        if (SPLIT) bl[nt] = *(const short8*)(BsL + o);
      }
#pragma unroll
      for (int mt = 0; mt < MT; ++mt)
#pragma unroll
        for (int nt = 0; nt < MT; ++nt) {
          acc[mt][nt] = __builtin_amdgcn_mfma_f32_16x16x32_bf16(a[mt], b[nt], acc[mt][nt], 0, 0, 0);
          if (SPLIT) {
            acc[mt][nt] = __builtin_amdgcn_mfma_f32_16x16x32_bf16(a[mt], bl[nt], acc[mt][nt], 0, 0, 0);
            acc[mt][nt] = __builtin_amdgcn_mfma_f32_16x16x32_bf16(al[mt], b[nt], acc[mt][nt], 0, 0, 0);
          }
        }
    }
  }

#pragma unroll
  for (int mt = 0; mt < MT; ++mt)
#pragma unroll
    for (int nt = 0; nt < MT; ++nt)
#pragma unroll
      for (int r = 0; r < 4; ++r) {
        const int row = row0 + wm + mt * 16 + jj * 4 + r;
        const int col = col0 + wn + nt * 16 + r16;
        const float v = acc[mt][nt][r];
        if (MODE == 3) {
          const long i = bz * bsC + (long)row * 512 + col;
          const bf16 h = f2b(v);
          Whi[i] = h;
          Wlo[i] = f2b(v - b2f(h));
        } else if (MODE == 4) {
          const long i = bz * bsC + (long)row * 512 + col;
          const float nv = alpha * Xf[i] + beta * v;
          Xf[i] = nv;
          const bf16 h = f2b(nv);
          const bf16 l = f2b(nv - b2f(h));
          Whi[i] = h; Wlo[i] = l;
          const long it2 = bz * bsC + (long)col * 512 + row;
          Thi[it2] = h; Tlo[it2] = l;
        }
      }
}

// ---------------------------------------------------------------------------
// m97-structure 128x128 NT GEMM: BK=64, 256 threads (4 waves 2x2, 64x64 out
// per wave), 32 KiB static LDS single-buffered, plain 2-barrier K-loop.
// Mechanism: __launch_bounds__(256,4) -> ~4 blocks/CU co-resident; the
// barrier/staging drain of one block overlaps other blocks' MFMA (m114).
// LDS layout [k>>3][row 0..127][8] -> linear gload_lds dest, b128 frag reads.
// C[m,n] = sum_k A[m,k]*B[n,k]; A,B bf16 row-major.
// MODE 0: bf16 store (LDS-coalesced)  MODE 1: GELU bf16  MODE 2: fp32 res+acc
// PSCAN: A row t = [q[t-d] (k<512, clamped to batch start) | q[t]] from QV
// (lda 1024); clamped rows produce garbage discarded by the combine.
// ---------------------------------------------------------------------------
template <int MODE, bool PSCAN>
__global__ __launch_bounds__(256, 4) void gemm128(
    const bf16* __restrict__ A, const bf16* __restrict__ B, int K, int lda,
    int ldb, bf16* __restrict__ outb, int ldo, const float* __restrict__ resf,
    float* __restrict__ outf, int d, int start, int nyb) {
  __shared__ bf16 smem[16384];  // 32 KB: As 16KB | Bs 16KB (Cs reuses all)
  bf16* As = smem;
  bf16* Bs = smem + 8192;

  const int t = threadIdx.x;
  const int lane = t & 63;
  const int w = t >> 6, wr = w >> 1, wc = w & 1;
  const int jj = lane >> 4, r16 = lane & 15;

  int row0, batch0 = 0;
  if (PSCAN) {
    const int b = blockIdx.x / nyb;
    const int ty = blockIdx.x - b * nyb;
    batch0 = b * 4096;
    row0 = batch0 + start + ty * 128;
  } else {
    row0 = blockIdx.x * 128;
  }
  const int col0 = blockIdx.y * 128;

  f32x4 acc[4][4] = {};

  for (int k0 = 0; k0 < K; k0 += 64) {
    __syncthreads();
#pragma unroll
    for (int s = 0; s < 4; ++s) {
      const int L = s * 256 + t;
      const int m = L & 127, cj = L >> 7;  // cj 0..7: k-chunk
      const int k = k0 + cj * 8;
      long ga;
      if (PSCAN) {
        const int rr = row0 + m;
        if (k < 512) {                  // k in [0,512): row t-d, clamped
          int rs = rr - d;
          if (rs < batch0) rs = batch0;  // garbage row, discarded by combine
          ga = (long)rs * 1024 + k;
        } else {                         // k in [512,1024): row t
          ga = (long)rr * 1024 + (k - 512);
        }
      } else {
        ga = (long)(row0 + m) * lda + k;
      }
      gload16(A + ga, As + L * 8);
      gload16(B + (long)(col0 + m) * ldb + k, Bs + L * 8);
    }
    __syncthreads();

#pragma unroll
    for (int kk = 0; kk < 2; ++kk) {
      short8 a[4], b[4];
#pragma unroll
      for (int mt = 0; mt < 4; ++mt)
        a[mt] = *(const short8*)(As + ((kk * 4 + jj) * 128 + wr * 64 + mt * 16 + r16) * 8);
#pragma unroll
      for (int nt = 0; nt < 4; ++nt)
        b[nt] = *(const short8*)(Bs + ((kk * 4 + jj) * 128 + wc * 64 + nt * 16 + r16) * 8);
#pragma unroll
      for (int mt = 0; mt < 4; ++mt)
#pragma unroll
        for (int nt = 0; nt < 4; ++nt)
          acc[mt][nt] = __builtin_amdgcn_mfma_f32_16x16x32_bf16(
              a[mt], b[nt], acc[mt][nt], 0, 0, 0);
    }
  }

  if constexpr (MODE == 2) {
#pragma unroll
    for (int mt = 0; mt < 4; ++mt)
#pragma unroll
      for (int nt = 0; nt < 4; ++nt)
#pragma unroll
        for (int r = 0; r < 4; ++r) {
          const int row = row0 + wr * 64 + mt * 16 + jj * 4 + r;
          const int col = col0 + wc * 64 + nt * 16 + r16;
          const long i = (long)row * ldo + col;
          outf[i] = resf[i] + acc[mt][nt][r];
        }
  } else {
    // MODE 0/1: coalesced bf16 epilogue through LDS (Cs = 128x128 bf16, 32KB)
    __syncthreads();
    bf16* Cs = smem;
#pragma unroll
    for (int mt = 0; mt < 4; ++mt)
#pragma unroll
      for (int nt = 0; nt < 4; ++nt)
#pragma unroll
        for (int r = 0; r < 4; ++r) {
          const int row = wr * 64 + mt * 16 + jj * 4 + r;
          const int col = wc * 64 + nt * 16 + r16;
          float v = acc[mt][nt][r];
          if (MODE == 1) v = gelu_exact(v);
          Cs[row * 128 + col] = f2b(v);
        }
    __syncthreads();
#pragma unroll
    for (int i = 0; i < 8; ++i) {
      const int rl = t / 16 + i * 16;
      const int cl = (t % 16) * 8;
      *(short8*)(outb + (long)(row0 + rl) * ldo + (col0 + cl)) =
          *(const short8*)(Cs + rl * 128 + cl);
    }
  }
}

// Pcat[c][k] = k<512 ? P1[c][k] : P2[c][k-512]; P1=Xhi[0..], P2=Xhi[262144..].
__global__ __launch_bounds__(256) void repack_pcat(const bf16* __restrict__ Xhi,
                                                   bf16* __restrict__ Pcat) {
  const int e = (blockIdx.x * 256 + threadIdx.x) << 3;  // 524288 elems
  const int c = e >> 10, k = e & 1023;
  const bf16* src = (k < 512) ? (Xhi + (long)c * 512 + k)
                              : (Xhi + 262144 + (long)c * 512 + (k - 512));
  *(short8*)(Pcat + e) = *(const short8*)src;
}

// ---------------------------------------------------------------------------
// Frobenius norm^2 of W1, W2 (512x512 each).
// ---------------------------------------------------------------------------
__global__ __launch_bounds__(256) void fnorm(const float* __restrict__ W1,
                                             const float* __restrict__ W2,
                                             float* __restrict__ sigsq) {
  const int b = blockIdx.x >> 8;
  const float4 v = *(const float4*)((b ? W2 : W1) +
                                    (((long)(blockIdx.x & 255) * 256 + threadIdx.x) << 2));
  float s = v.x * v.x + v.y * v.y + v.z * v.z + v.w * v.w;
  s = wave_sum(s);
  if ((threadIdx.x & 63) == 0) atomicAdd(&sigsq[b], s);
}

// X0 = W / ||W||_F; emit fp32 master + hi/lo splits + transposed splits.
__global__ __launch_bounds__(256) void scale_init(
    const float* __restrict__ W1, const float* __restrict__ W2,
    const float* __restrict__ sigsq, float* __restrict__ Xf,
    bf16* __restrict__ Xhi, bf16* __restrict__ Xlo,
    bf16* __restrict__ Thi, bf16* __restrict__ Tlo) {
  const long idx = (long)blockIdx.x * 256 + threadIdx.x;  // 2*262144 total
  const int b = (int)(idx >> 18);
  const int i = (int)(idx & 262143);
  const float s = rsqrtf(sigsq[b]);
  const float val = (b ? W2[i] : W1[i]) * s;
  const long o = ((long)b << 18) + i;
  Xf[o] = val;
  const bf16 h = f2b(val);
  const bf16 l = f2b(val - b2f(h));
  Xhi[o] = h; Xlo[o] = l;
  const int r = i >> 9, c = i & 511;
  const long ot = ((long)b << 18) + (long)c * 512 + r;
  Thi[ot] = h; Tlo[ot] = l;
}

// All five weight matrices fp32 -> bf16 in one launch (4 elems/thread).
__global__ __launch_bounds__(256) void convert_weights(
    const float* __restrict__ Wq, const float* __restrict__ Wv,
    const float* __restrict__ Wo, const float* __restrict__ Wfc,
    const float* __restrict__ Wpr, bf16* __restrict__ Wqvb,
    bf16* __restrict__ Wob, bf16* __restrict__ Wfcb, bf16* __restrict__ Wprb) {
  const long e = ((long)blockIdx.x * 256 + threadIdx.x) << 2;
  const float* src; bf16* dst; long off;
  if (e < 262144)       { src = Wq;  dst = Wqvb;          off = e; }
  else if (e < 524288)  { src = Wv;  dst = Wqvb + 262144; off = e - 262144; }
  else if (e < 786432)  { src = Wo;  dst = Wob;           off = e - 524288; }
  else if (e < 1835008) { src = Wfc; dst = Wfcb;          off = e - 786432; }
  else                  { src = Wpr; dst = Wprb;          off = e - 1835008; }
  const float4 v = *(const float4*)(src + off);
  short4v o4;
  o4[0] = f2sb(v.x); o4[1] = f2sb(v.y); o4[2] = f2sb(v.z); o4[3] = f2sb(v.w);
  *(short4v*)(dst + off) = o4;
}

// LayerNorm over C=512, one wave per row (4 rows/block), bf16 out.
__global__ __launch_bounds__(256) void ln_rows(const float* __restrict__ x,
                                               const float* __restrict__ w,
                                               bf16* __restrict__ out) {
  const int row = (blockIdx.x << 2) + (threadIdx.x >> 6);
  const int lane = threadIdx.x & 63;
  const float* xr = x + (long)row * 512 + lane * 8;
  const float4 a = *(const float4*)xr;
  const float4 b = *(const float4*)(xr + 4);
  float v[8] = {a.x, a.y, a.z, a.w, b.x, b.y, b.z, b.w};
  float s1 = 0.f, s2 = 0.f;
#pragma unroll
  for (int i = 0; i < 8; ++i) { s1 += v[i]; s2 += v[i] * v[i]; }
  s1 = wave_allsum(s1);
  s2 = wave_allsum(s2);
  const float mean = s1 * (1.0f / 512.0f);
  const float var = s2 * (1.0f / 512.0f) - mean * mean;
  const float inv = rsqrtf(var + 1e-5f);
  const float4 w1 = *(const float4*)(w + lane * 8);
  const float4 w2 = *(const float4*)(w + lane * 8 + 4);
  const float wv[8] = {w1.x, w1.y, w1.z, w1.w, w2.x, w2.y, w2.z, w2.w};
  short8 o8;
#pragma unroll
  for (int i = 0; i < 8; ++i) o8[i] = f2sb((v[i] - mean) * inv * wv[i]);
  *(short8*)(out + (long)row * 512 + lane * 8) = o8;
}

// pscan combine (S-form): q[t] = rmsnorm(S[t]) for t >= d; one wave per row.
__global__ __launch_bounds__(256) void pscan_combine(const bf16* __restrict__ S,
                                                     bf16* __restrict__ QV, int d) {
  const int span = 4096 - d;
  const int wid = (blockIdx.x << 2) + (threadIdx.x >> 6);
  const int lane = threadIdx.x & 63;
  const int b = wid / span;
  const int tt = d + (wid - b * span);
  const long rowQ = (long)b * 4096 + tt;
  const short8 s8 = *(const short8*)(S + rowQ * 512 + lane * 8);
  float s[8]; float ss = 0.f;
#pragma unroll
  for (int i = 0; i < 8; ++i) {
    const float v = sb2f(s8[i]);
    s[i] = v; ss += v * v;
  }
  ss = wave_allsum(ss);
  const float inv = rsqrtf(ss * (1.0f / 512.0f) + 1e-6f);
  short8 o8;
#pragma unroll
  for (int i = 0; i < 8; ++i) o8[i] = f2sb(s[i] * inv);
  *(short8*)(QV + rowQ * 1024 + lane * 8) = o8;
}

// u = q * v elementwise, 8 elems/thread.
__global__ __launch_bounds__(256) void qv_mul(const bf16* __restrict__ QV,
                                              bf16* __restrict__ u) {
  const long base = ((long)blockIdx.x * 256 + threadIdx.x) << 3;
  const long row = base >> 9;
  const int c = (int)(base & 511);
  const short8 q8 = *(const short8*)(QV + row * 1024 + c);
  const short8 v8 = *(const short8*)(QV + row * 1024 + 512 + c);
  short8 o8;
#pragma unroll
  for (int i = 0; i < 8; ++i) o8[i] = f2sb(sb2f(q8[i]) * sb2f(v8[i]));
  *(short8*)(u + row * 512 + c) = o8;
}

// ---------------------------------------------------------------------------
extern "C" void kernel_launch(void* const* d_in, const int* in_sizes, int n_in,
                              void* d_out, int out_size, void* d_ws, size_t ws_size,
                              hipStream_t stream) {
  (void)in_sizes; (void)n_in; (void)out_size; (void)ws_size;
  const float* x    = (const float*)d_in[0];
  const float* ln1w = (const float*)d_in[1];
  const float* Wq   = (const float*)d_in[2];
  const float* Wv   = (const float*)d_in[3];
  const float* Wo   = (const float*)d_in[4];
  // d_in[5] = identity: provably unused (positions t<d are never updated)
  const float* Wp1  = (const float*)d_in[6];
  const float* Wp2  = (const float*)d_in[7];
  const float* ln2w = (const float*)d_in[8];
  const float* Wfc  = (const float*)d_in[9];
  const float* Wpr  = (const float*)d_in[10];
  float* out = (float*)d_out;

  const long M = 16384;
  char* ws = (char*)d_ws;
  size_t off = 0;
  auto alloc = [&](size_t bytes) -> void* {
    void* p = ws + off;
    off += (bytes + 255) & ~(size_t)255;
    return p;
  };
  bf16* YZ   = (bf16*)alloc(M * 1024 * 2);   // S uses first 16MB; +QV = h3
  bf16* QV   = (bf16*)alloc(M * 1024 * 2);   // 32MB
  bf16* hb   = (bf16*)alloc(M * 512 * 2);    // h -> u -> h2
  bf16* Wqvb = (bf16*)alloc(1024 * 512 * 2);
  bf16* Wob  = (bf16*)alloc(512 * 512 * 2);
  bf16* Wfcb = (bf16*)alloc(2048 * 512 * 2);
  bf16* Wprb = (bf16*)alloc(512 * 2048 * 2);
  float* Xf  = (float*)alloc(2 * 262144 * 4);
  bf16* Xhi  = (bf16*)alloc(2 * 262144 * 2);  // final [P1;P2] bf16 (1024x512)
  bf16* Xlo  = (bf16*)alloc(2 * 262144 * 2);
  bf16* XtAh = (bf16*)alloc(2 * 262144 * 2);
  bf16* XtAl = (bf16*)alloc(2 * 262144 * 2);
  bf16* XtBh = (bf16*)alloc(2 * 262144 * 2);
  bf16* XtBl = (bf16*)alloc(2 * 262144 * 2);
  bf16* Ghi  = (bf16*)alloc(2 * 262144 * 2);
  bf16* Glo  = (bf16*)alloc(2 * 262144 * 2);
  bf16* Pcat = (bf16*)alloc(512 * 1024 * 2);  // [c][P1[c,:]|P2[c,:]]
  float* sig = (float*)alloc(256);
  bf16* S  = YZ;   // [16384][512] bf16, 16MB
  bf16* h3 = YZ;   // [16384,2048] bf16 spans YZ+QV (both dead by then)

  const auto Z0 = nullptr;

  // --- polar decomposition of Wp1, Wp2 (batched Newton-Schulz, split-bf16 MFMA)
  hipMemsetAsync(sig, 0, 2 * sizeof(float), stream);
  fnorm<<<512, 256, 0, stream>>>(Wp1, Wp2, sig);
  scale_init<<<2048, 256, 0, stream>>>(Wp1, Wp2, sig, Xf, Xhi, Xlo, XtAh, XtAl);

  bf16 *tch = XtAh, *tcl = XtAl, *tnh = XtBh, *tnl = XtBl;
  const long Sz = 262144;
  for (int i = 0; i < 20; ++i) {
    const bool pol = (i >= 16);          // 16 doublings + 4 polish
    const float ac = pol ? 1.5f : 2.0f;
    const float bc = pol ? -0.5f : -1.0f;
    dim3 g(8, 8, 2);
    gemm_nt<3, true, 64><<<g, 256, 32768, stream>>>(
        Xhi, Xlo, Xhi, Xlo, 512, 512, 512, Sz, Sz, Sz,
        0.f, 0.f, Z0, Ghi, Glo, Z0, Z0);
    gemm_nt<4, true, 64><<<g, 256, 32768, stream>>>(
        Ghi, Glo, tch, tcl, 512, 512, 512, Sz, Sz, Sz,
        ac, bc, Xf, Xhi, Xlo, tnh, tnl);
    bf16* sw;
    sw = tch; tch = tnh; tnh = sw;
    sw = tcl; tcl = tnl; tnl = sw;
  }
  repack_pcat<<<256, 256, 0, stream>>>(Xhi, Pcat);

  // --- weight conversions to bf16 (one launch)
  convert_weights<<<2816, 256, 0, stream>>>(Wq, Wv, Wo, Wfc, Wpr, Wqvb, Wob, Wfcb, Wprb);

  // --- SSM branch
  ln_rows<<<4096, 256, 0, stream>>>(x, ln1w, hb);
  // [q|v] = h @ [Wq;Wv]^T   (M=16384, N=1024, K=512)
  gemm128<0, false><<<dim3(128, 8), 256, 0, stream>>>(
      hb, Wqvb, 512, 512, 512, QV, 1024, Z0, Z0, 0, 0, 0);

  for (int d = 1; d < 4096; d <<= 1) {
    // S = [q[t-d]|q[t]] @ Pcat^T  (K=1024), rows [d&~127, 4096) per batch
    const int start = d & ~127;
    const int nyb = (4096 - start) >> 7;
    gemm128<0, true><<<dim3(4 * nyb, 4), 256, 0, stream>>>(
        QV, Pcat, 1024, 1024, 1024, S, 512, Z0, Z0, d, start, nyb);
    // q[t] = rmsnorm(S[t]) for t >= d
    pscan_combine<<<4096 - d, 256, 0, stream>>>(S, QV, d);
  }

  qv_mul<<<4096, 256, 0, stream>>>(QV, hb);  // u -> hb
  // x2 = x + u @ Wo^T  -> d_out (fp32)
  gemm128<2, false><<<dim3(128, 4), 256, 0, stream>>>(
      hb, Wob, 512, 512, 512, Z0, 512, x, out, 0, 0, 0);

  // --- MLP branch
  ln_rows<<<4096, 256, 0, stream>>>(out, ln2w, hb);  // h2 -> hb
  gemm128<1, false><<<dim3(128, 16), 256, 0, stream>>>(
      hb, Wfcb, 512, 512, 512, h3, 2048, Z0, Z0, 0, 0, 0);
  gemm128<2, false><<<dim3(128, 4), 256, 0, stream>>>(
      h3, Wprb, 2048, 2048, 2048, Z0, 512, out, out, 0, 0, 0);
}